// Round 1
// baseline (157.997 us; speedup 1.0000x reference)
//
#include <hip/hip_runtime.h>

#define HID 4096
#define MD  128
#define SB  32768          // B*S rows total
#define SLEN 4096
#define NB  8
#define NH  10
#define WIN 10
#define TLEN (SLEN - WIN + 1)   // 4087
#define BM  64
#define BK  64
#define NEGV -1000000000.0f

typedef _Float16 f16x8 __attribute__((ext_vector_type(8)));
typedef float f32x4 __attribute__((ext_vector_type(4)));

__device__ __forceinline__ unsigned short f2h(float f) {
  _Float16 h = (_Float16)f;
  return __builtin_bit_cast(unsigned short, h);
}

__device__ __forceinline__ void gl_lds16(const void* g, void* l) {
  __builtin_amdgcn_global_load_lds(
      (const __attribute__((address_space(1))) void*)g,
      (__attribute__((address_space(3))) void*)l, 16, 0, 0);
}

// ---------------- weight preconvert: fp32 -> fp16 planes in ws ----------------
__global__ void convert_k(const float* __restrict__ W1, const float* __restrict__ W2,
                          const float* __restrict__ Wq, const float* __restrict__ Wv,
                          unsigned short* __restrict__ w1h, unsigned short* __restrict__ w2h,
                          unsigned short* __restrict__ wqvh) {
  int i = blockIdx.x * 256 + threadIdx.x;
  if (i < MD * HID) w1h[i] = f2h(W1[i]);
  if (i < MD * MD)  w2h[i] = f2h(W2[i]);
  if (i < 32 * MD) {                       // 32 padded rows: 0-9 Wq, 10-19 Wv, 20-31 zero
    unsigned short v = 0;
    if (i < NH * MD)          v = f2h(Wq[i]);
    else if (i < 2 * NH * MD) v = f2h(Wv[i - NH * MD]);
    wqvh[i] = v;
  }
}

// ---------------- fused MLP + heads: x -> logits/vals planes ----------------
// grid 512 blocks x 256 thr. Per block: 64 rows.
// LDS: As dbuf 2x[64][128B] @0 (16KB) | Bs dbuf 2x[128][128B] @16384 (32KB) | Wqv [32][256B] @49152 (8KB)
// reuse: Y [64][256B] @0, W2s [128][256B] @16384
__global__ __launch_bounds__(256, 2) void fused_mlp(
    const float* __restrict__ x,
    const float* __restrict__ b1g, const float* __restrict__ b2g,
    const float* __restrict__ bvg,
    const unsigned short* __restrict__ w1h, const unsigned short* __restrict__ w2h,
    const unsigned short* __restrict__ wqvh,
    float* __restrict__ lv)
{
  __shared__ __align__(16) char smem[57344];
  char* AsB  = smem;
  char* BsB  = smem + 16384;
  char* WqvS = smem + 49152;
  char* Y    = smem;          // reuse after K-loop
  char* W2s  = smem + 16384;  // reuse after K-loop

  const int tid  = threadIdx.x;
  const int lane = tid & 63;
  const int w    = tid >> 6;
  const int wr   = w >> 1, wc = w & 1;
  const int l15  = lane & 15;
  const int lk16 = (lane >> 4) * 16;
  const int m0   = blockIdx.x * BM;

  // stage Wqv once (8KB)
  #pragma unroll
  for (int c = 0; c < 2; ++c) {
    int tb = (c * 256 + tid) * 16;
    int row = tb >> 8, kb = tb & 255;
    int kbs = kb ^ ((row & 7) << 4);
    gl_lds16(wqvh + row * MD + (kbs >> 1), WqvS + c * 4096 + w * 1024);
  }

  f32x4 acc[2][4] = {};

  // prologue: stage kt=0 into buf0
  {
    #pragma unroll
    for (int c = 0; c < 4; ++c) {
      int tb = (c * 256 + tid) * 16;
      int row = tb >> 7, kb = tb & 127;
      int kbs = kb ^ ((row & 7) << 4);
      gl_lds16(w1h + row * HID + (kbs >> 1), BsB + c * 4096 + w * 1024);
    }
    #pragma unroll
    for (int p = 0; p < 4; ++p) {
      int arow = p * 16 + (tid >> 4);
      int akq  = tid & 15;
      float4 v = *(const float4*)(x + (size_t)(m0 + arow) * HID + akq * 4);
      ushort4 o; o.x = f2h(v.x); o.y = f2h(v.y); o.z = f2h(v.z); o.w = f2h(v.w);
      int kb = (akq * 8) ^ ((arow & 7) << 4);
      *(ushort4*)(AsB + arow * 128 + kb) = o;
    }
  }
  __syncthreads();

  for (int kt = 0; kt < HID / BK; ++kt) {
    const int cur = kt & 1;
    const char* Ac = AsB + cur * 8192;
    const char* Bc = BsB + cur * 16384;
    float4 av[4];
    const bool pre = (kt < HID / BK - 1);
    if (pre) {
      const int k0n = (kt + 1) * BK;
      #pragma unroll
      for (int c = 0; c < 4; ++c) {
        int tb = (c * 256 + tid) * 16;
        int row = tb >> 7, kb = tb & 127;
        int kbs = kb ^ ((row & 7) << 4);
        gl_lds16(w1h + row * HID + k0n + (kbs >> 1),
                 BsB + (cur ^ 1) * 16384 + c * 4096 + w * 1024);
      }
      #pragma unroll
      for (int p = 0; p < 4; ++p) {
        int arow = p * 16 + (tid >> 4);
        int akq  = tid & 15;
        av[p] = *(const float4*)(x + (size_t)(m0 + arow) * HID + k0n + akq * 4);
      }
    }
    f16x8 af[2][2], bfr[4][2];
    #pragma unroll
    for (int ks = 0; ks < 2; ++ks) {
      int kb = ks * 64 + lk16;
      #pragma unroll
      for (int mf = 0; mf < 2; ++mf) {
        int row = wr * 32 + mf * 16 + l15;
        af[mf][ks] = *(const f16x8*)(Ac + row * 128 + (kb ^ ((row & 7) << 4)));
      }
      #pragma unroll
      for (int nf = 0; nf < 4; ++nf) {
        int col = wc * 64 + nf * 16 + l15;
        bfr[nf][ks] = *(const f16x8*)(Bc + col * 128 + (kb ^ ((col & 7) << 4)));
      }
    }
    #pragma unroll
    for (int ks = 0; ks < 2; ++ks)
      #pragma unroll
      for (int mf = 0; mf < 2; ++mf)
        #pragma unroll
        for (int nf = 0; nf < 4; ++nf)
          acc[mf][nf] = __builtin_amdgcn_mfma_f32_16x16x32_f16(af[mf][ks], bfr[nf][ks], acc[mf][nf], 0, 0, 0);
    if (pre) {
      #pragma unroll
      for (int p = 0; p < 4; ++p) {
        int arow = p * 16 + (tid >> 4);
        int akq  = tid & 15;
        ushort4 o; o.x = f2h(av[p].x); o.y = f2h(av[p].y); o.z = f2h(av[p].z); o.w = f2h(av[p].w);
        int kb = (akq * 8) ^ ((arow & 7) << 4);
        *(ushort4*)(AsB + (cur ^ 1) * 8192 + arow * 128 + kb) = o;
      }
    }
    __syncthreads();
  }

  // stage W2 (32KB) into Bs region
  #pragma unroll
  for (int c = 0; c < 8; ++c) {
    int tb = (c * 256 + tid) * 16;
    int row = tb >> 8, kb = tb & 255;
    int kbs = kb ^ ((row & 7) << 4);
    gl_lds16(w2h + row * MD + (kbs >> 1), W2s + c * 4096 + w * 1024);
  }
  // y1 = relu(acc + b1) -> Y (fp16, swizzled 256B rows)
  #pragma unroll
  for (int nf = 0; nf < 4; ++nf) {
    float bb = b1g[wc * 64 + nf * 16 + l15];
    #pragma unroll
    for (int mf = 0; mf < 2; ++mf)
      #pragma unroll
      for (int r = 0; r < 4; ++r) {
        float t = acc[mf][nf][r] + bb; t = t > 0.f ? t : 0.f;
        int row = wr * 32 + mf * 16 + (lane >> 4) * 4 + r;
        int col = wc * 64 + nf * 16 + l15;
        *(unsigned short*)(Y + row * 256 + ((col * 2) ^ ((row & 7) << 4))) = f2h(t);
      }
  }
  __syncthreads();

  // layer 2: y2 = relu(y1 @ W2^T + b2), K=128
  f32x4 acc2[2][4] = {};
  #pragma unroll
  for (int ks = 0; ks < 4; ++ks) {
    int kb = ks * 64 + lk16;
    f16x8 a2[2], b2f[4];
    #pragma unroll
    for (int mf = 0; mf < 2; ++mf) {
      int row = wr * 32 + mf * 16 + l15;
      a2[mf] = *(const f16x8*)(Y + row * 256 + (kb ^ ((row & 7) << 4)));
    }
    #pragma unroll
    for (int nf = 0; nf < 4; ++nf) {
      int col = wc * 64 + nf * 16 + l15;
      b2f[nf] = *(const f16x8*)(W2s + col * 256 + (kb ^ ((col & 7) << 4)));
    }
    #pragma unroll
    for (int mf = 0; mf < 2; ++mf)
      #pragma unroll
      for (int nf = 0; nf < 4; ++nf)
        acc2[mf][nf] = __builtin_amdgcn_mfma_f32_16x16x32_f16(a2[mf], b2f[nf], acc2[mf][nf], 0, 0, 0);
  }
  __syncthreads();    // all Y reads done before overwrite
  #pragma unroll
  for (int nf = 0; nf < 4; ++nf) {
    float bb = b2g[wc * 64 + nf * 16 + l15];
    #pragma unroll
    for (int mf = 0; mf < 2; ++mf)
      #pragma unroll
      for (int r = 0; r < 4; ++r) {
        float t = acc2[mf][nf][r] + bb; t = t > 0.f ? t : 0.f;
        int row = wr * 32 + mf * 16 + (lane >> 4) * 4 + r;
        int col = wc * 64 + nf * 16 + l15;
        *(unsigned short*)(Y + row * 256 + ((col * 2) ^ ((row & 7) << 4))) = f2h(t);
      }
  }
  __syncthreads();

  // layer 3: heads. wave w handles rows [w*16, w*16+16), cols 0..31 (20 valid)
  f32x4 acc3[2] = {};
  #pragma unroll
  for (int ks = 0; ks < 4; ++ks) {
    int kb = ks * 64 + lk16;
    int row = w * 16 + l15;
    f16x8 a3 = *(const f16x8*)(Y + row * 256 + (kb ^ ((row & 7) << 4)));
    #pragma unroll
    for (int nt = 0; nt < 2; ++nt) {
      int col = nt * 16 + l15;
      f16x8 b3 = *(const f16x8*)(WqvS + col * 256 + (kb ^ ((col & 7) << 4)));
      acc3[nt] = __builtin_amdgcn_mfma_f32_16x16x32_f16(a3, b3, acc3[nt], 0, 0, 0);
    }
  }
  #pragma unroll
  for (int nt = 0; nt < 2; ++nt) {
    int col = nt * 16 + l15;
    #pragma unroll
    for (int r = 0; r < 4; ++r) {
      int row = w * 16 + (lane >> 4) * 4 + r;
      int s = m0 + row;
      float t = acc3[nt][r];
      if (col < NH) lv[(size_t)col * SB + s] = t;                     // logits plane
      else if (col < 2 * NH) lv[(size_t)col * SB + s] = t + bvg[col - NH]; // vals plane (+bv)
    }
  }
}

// ---------------- sliding-window softmax + per-chunk max ----------------
// grid (16 chunks, 8 batch, 10 heads) x 256 thr
__global__ void windows_k(const float* __restrict__ lv, const int* __restrict__ mask,
                          float* __restrict__ partial) {
  const int chunk = blockIdx.x, b = blockIdx.y, h = blockIdx.z;
  const int t0 = chunk * 256;
  const int tid = threadIdx.x;
  __shared__ float lsh[272], vsh[272];
  const float* lp = lv + (size_t)h * SB + b * SLEN;
  const float* vp = lv + (size_t)(NH + h) * SB + b * SLEN;
  const int* mp = mask + b * SLEN;
  for (int i = tid; i < 256 + WIN - 1; i += 256) {
    int t = t0 + i;
    if (t < SLEN) {
      float l = lp[t];
      if (mp[t] == 0) l = NEGV;
      lsh[i] = l; vsh[i] = vp[t];
    }
  }
  __syncthreads();
  float wmax = -INFINITY;
  int t = t0 + tid;
  if (t < TLEN) {
    float m = lsh[tid];
    #pragma unroll
    for (int j = 1; j < WIN; ++j) m = fmaxf(m, lsh[tid + j]);
    float den = 0.f, num = 0.f;
    #pragma unroll
    for (int j = 0; j < WIN; ++j) {
      float e = __expf(lsh[tid + j] - m);
      den += e; num += e * vsh[tid + j];
    }
    wmax = num / den;
  }
  #pragma unroll
  for (int o = 32; o > 0; o >>= 1) wmax = fmaxf(wmax, __shfl_down(wmax, o, 64));
  __shared__ float red[4];
  if ((tid & 63) == 0) red[tid >> 6] = wmax;
  __syncthreads();
  if (tid == 0) {
    float r = fmaxf(fmaxf(red[0], red[1]), fmaxf(red[2], red[3]));
    partial[(b * NH + h) * 16 + chunk] = r;
  }
}

// ---------------- final: max over chunks, sum heads, + bias ----------------
__global__ void finalize_k(const float* __restrict__ partial, const float* __restrict__ bias,
                           float* __restrict__ out) {
  const int tid = threadIdx.x;  // 1 block, 128 thr
  __shared__ float hm[80];
  if (tid < NB * NH) {
    float m = -INFINITY;
    #pragma unroll
    for (int c = 0; c < 16; ++c) m = fmaxf(m, partial[tid * 16 + c]);
    hm[tid] = m;
  }
  __syncthreads();
  if (tid < NB) {
    float s = bias[0];
    #pragma unroll
    for (int h = 0; h < NH; ++h) s += hm[tid * NH + h];
    out[tid] = s;
  }
}

extern "C" void kernel_launch(void* const* d_in, const int* in_sizes, int n_in,
                              void* d_out, int out_size, void* d_ws, size_t ws_size,
                              hipStream_t stream) {
  const float* x    = (const float*)d_in[0];
  const int*   mask = (const int*)d_in[1];
  const float* W1   = (const float*)d_in[2];
  const float* b1   = (const float*)d_in[3];
  const float* W2   = (const float*)d_in[4];
  const float* b2   = (const float*)d_in[5];
  const float* Wq   = (const float*)d_in[6];
  const float* Wv   = (const float*)d_in[7];
  const float* bv   = (const float*)d_in[8];
  const float* bias = (const float*)d_in[9];

  char* ws = (char*)d_ws;
  unsigned short* w1h  = (unsigned short*)ws;                   // 1,048,576 B
  unsigned short* w2h  = (unsigned short*)(ws + 1048576);       //    32,768 B
  unsigned short* wqvh = (unsigned short*)(ws + 1081344);       //     8,192 B
  float* lv            = (float*)(ws + 1089536);                // 20*32768*4 = 2,621,440 B
  float* partial       = (float*)(ws + 3710976);                //     5,120 B
  float* out = (float*)d_out;

  hipLaunchKernelGGL(convert_k, dim3(2048), dim3(256), 0, stream, W1, W2, Wq, Wv, w1h, w2h, wqvh);
  hipLaunchKernelGGL(fused_mlp, dim3(SB / BM), dim3(256), 0, stream,
                     x, b1, b2, bv, w1h, w2h, wqvh, lv);
  hipLaunchKernelGGL(windows_k, dim3(16, NB, NH), dim3(256), 0, stream, lv, mask, partial);
  hipLaunchKernelGGL(finalize_k, dim3(1), dim3(128), 0, stream, partial, bias, out);
}